// Round 20
// baseline (112.215 us; speedup 1.0000x reference)
//
#include <hip/hip_runtime.h>
#include <cstdint>

#define LTOK 12544
#define BATCH 2
#define CDIM 128
#define C3 384
#define RES 112
#define NROWS (BATCH * LTOK)  // 25088
#define CHUNKS 784            // 32-row chunks
#define GRID 256
#define SCALE 0.17677669529663687f       // 1/sqrt(32)
#define SCALE_L2E 0.25505578188526813f   // SCALE * log2(e)

typedef __attribute__((ext_vector_type(8))) short bf16x8;
typedef __attribute__((ext_vector_type(4))) float f32x4;

__device__ inline ushort f2b(float f) {
    union { float f; unsigned u; } v; v.f = f;
    unsigned r = (v.u + 0x7FFFu + ((v.u >> 16) & 1u)) >> 16;
    return (ushort)r;
}
__device__ inline ushort f2b_t(float f) {   // truncating bf16 (P-pack only)
    union { float f; unsigned u; } v; v.f = f;
    return (ushort)(v.u >> 16);
}
__device__ inline float b2f(ushort u) {
    union { float f; unsigned u; } v; v.u = ((unsigned)u) << 16; return v.f;
}
// tanh-form GELU via hw exp
__device__ inline float gelu_f(float a) {
    float u2 = 1.5957691216f * (a + 0.044715f * a * a * a);
    return a - a / (__expf(u2) + 1.0f);
}

// map window-local token n -> (i, j); branch 0: W_sp=7, branch 1: W_sp=112
__device__ inline void nij(int n, int branch, int& i, int& j) {
    if (branch == 0) { i = n / 7; j = n - i * 7; }
    else             { i = n / 112; j = n - i * 112; }
}

// ---------------- K0: convert all weights to bf16 ----------------
__global__ __launch_bounds__(256) void k_cvt(const float* __restrict__ w0, const float* __restrict__ w1,
        const float* __restrict__ w2, const float* __restrict__ w3,
        ushort* __restrict__ o0, ushort* __restrict__ o1,
        ushort* __restrict__ o2, ushort* __restrict__ o3)
{
    int idx = blockIdx.x * 256 + threadIdx.x;  // vec4 index
    const float* src; ushort* dst; int vi;
    if      (idx < 12288) { src = w0; dst = o0; vi = idx; }
    else if (idx < 16384) { src = w1; dst = o1; vi = idx - 12288; }
    else if (idx < 32768) { src = w2; dst = o2; vi = idx - 16384; }
    else                  { src = w3; dst = o3; vi = idx - 32768; }
    float4 v = ((const float4*)src)[vi];
    ushort4 r; r.x = f2b(v.x); r.y = f2b(v.y); r.z = f2b(v.z); r.w = f2b(v.w);
    ((ushort4*)dst)[vi] = r;
}

// ---------------- K1: LN1 + QKV GEMM, weight-stationary grid-stride (R14-proven) ----------------
__global__ __launch_bounds__(512) void k_ln_qkv(const float* __restrict__ x,
        const float* __restrict__ g1, const float* __restrict__ b1,
        const ushort* __restrict__ wqkv_bf, ushort* __restrict__ qkv)
{
    __shared__ ushort ys[32 * 136];
    const int tid = threadIdx.x;
    const int wv = tid >> 6, lane = tid & 63;
    const int c16 = lane & 15, g = lane >> 4;

    bf16x8 wr[3][4];
    #pragma unroll
    for (int t = 0; t < 3; ++t)
        #pragma unroll
        for (int kc = 0; kc < 4; ++kc)
            wr[t][kc] = *(const bf16x8*)&wqkv_bf[(wv * 48 + t * 16 + c16) * CDIM + kc * 32 + g * 8];

    const int r = tid >> 4, l16 = tid & 15;
    float4 gv0 = *(const float4*)(g1 + l16 * 8);
    float4 gv4 = *(const float4*)(g1 + l16 * 8 + 4);
    float4 bv0 = *(const float4*)(b1 + l16 * 8);
    float4 bv4 = *(const float4*)(b1 + l16 * 8 + 4);

    for (int c = blockIdx.x; c < CHUNKS; c += GRID) {
        const long long row0 = (long long)c * 32;

        {
            const float* xr = x + (row0 + r) * CDIM + l16 * 8;
            float4 a0 = *(const float4*)xr;
            float4 a1 = *(const float4*)(xr + 4);
            float s  = a0.x + a0.y + a0.z + a0.w + a1.x + a1.y + a1.z + a1.w;
            float s2 = a0.x*a0.x + a0.y*a0.y + a0.z*a0.z + a0.w*a0.w
                     + a1.x*a1.x + a1.y*a1.y + a1.z*a1.z + a1.w*a1.w;
            #pragma unroll
            for (int m = 8; m >= 1; m >>= 1) { s += __shfl_xor(s, m, 16); s2 += __shfl_xor(s2, m, 16); }
            const float mean = s * (1.f / 128.f);
            const float var = s2 * (1.f / 128.f) - mean * mean;
            const float rs = rsqrtf(var + 1e-5f);
            ushort4 w0, w1;
            w0.x = f2b((a0.x - mean) * rs * gv0.x + bv0.x);
            w0.y = f2b((a0.y - mean) * rs * gv0.y + bv0.y);
            w0.z = f2b((a0.z - mean) * rs * gv0.z + bv0.z);
            w0.w = f2b((a0.w - mean) * rs * gv0.w + bv0.w);
            w1.x = f2b((a1.x - mean) * rs * gv4.x + bv4.x);
            w1.y = f2b((a1.y - mean) * rs * gv4.y + bv4.y);
            w1.z = f2b((a1.z - mean) * rs * gv4.z + bv4.z);
            w1.w = f2b((a1.w - mean) * rs * gv4.w + bv4.w);
            *(ushort4*)&ys[r * 136 + l16 * 8]     = w0;
            *(ushort4*)&ys[r * 136 + l16 * 8 + 4] = w1;
        }
        __syncthreads();   // B1: ys ready

        bf16x8 yb[2][4];
        #pragma unroll
        for (int mt = 0; mt < 2; ++mt)
            #pragma unroll
            for (int kc = 0; kc < 4; ++kc)
                yb[mt][kc] = *(const bf16x8*)&ys[(mt * 16 + c16) * 136 + kc * 32 + g * 8];
        __syncthreads();   // B2: all yb reads done

        #pragma unroll
        for (int t = 0; t < 3; ++t) {
            const int n0 = wv * 48 + t * 16;
            #pragma unroll
            for (int mt = 0; mt < 2; ++mt) {
                f32x4 acc = {0.f, 0.f, 0.f, 0.f};
                #pragma unroll
                for (int kc = 0; kc < 4; ++kc)
                    acc = __builtin_amdgcn_mfma_f32_16x16x32_bf16(wr[t][kc], yb[mt][kc], acc, 0, 0, 0);
                ushort4 sv;
                sv.x = f2b(acc[0]); sv.y = f2b(acc[1]); sv.z = f2b(acc[2]); sv.w = f2b(acc[3]);
                *(ushort4*)&qkv[(row0 + mt * 16 + c16) * C3 + n0 + g * 4] = sv;
            }
        }
    }
}

// ---------------- K2: windowed attention + LEPE via bf16 MFMA (R14-proven + exp2 fold) ----------------
__global__ __launch_bounds__(256) void k_attn_mfma(const ushort* __restrict__ qkv,
        const float* __restrict__ cw0, const float* __restrict__ cb0,
        const float* __restrict__ cw1, const float* __restrict__ cb1,
        ushort* __restrict__ att)
{
    __shared__ __align__(16) ushort ks[112 * 40];
    __shared__ __align__(16) ushort vt[32 * 136];
    __shared__ __align__(16) ushort pl[4][16 * 40];
    __shared__ __align__(16) float  ol[4][16 * 36];

    const int tid = threadIdx.x;
    const int wv = tid >> 6, lane = tid & 63;
    const int g = lane >> 4, c16 = lane & 15;

    const int wh = blockIdx.x;
    const int branch = wh >> 6;
    const int idx = wh & 63;
    const int win = idx >> 1, head = idx & 1;
    const int b = win >> 4, w = win & 15;
    const int rowBase = branch ? w * 7 : 0;
    const int colBase = branch ? 0 : w * 7;
    const float* cw = branch ? cw1 : cw0;
    const float* cb = branch ? cb1 : cb0;
    const int cbase = branch * 64 + head * 32;
    const long long qkvB = (long long)b * LTOK * C3;

    {
        const int row = tid >> 3, cwd = tid & 7;
        *(unsigned*)&vt[row * 136 + 112 + cwd * 2] = 0u;
    }

    const int t0 = blockIdx.y * 7 + 2 * wv;
    const int nt = (2 * wv + 1 < 7) ? 2 : 1;

    // Q pre-scaled by (1/sqrt(d)) * log2(e): S is then in log2 domain, exp(s)=exp2(S)
    bf16x8 qf[2];
    #pragma unroll
    for (int t = 0; t < 2; ++t) if (t < nt) {
        int n = (t0 + t) * 16 + c16;
        int i, j; nij(n, branch, i, j);
        const ushort* qp = qkv + qkvB + (long long)((rowBase + i) * RES + colBase + j) * C3 + cbase + g * 8;
        bf16x8 qq = *(const bf16x8*)qp;
        #pragma unroll
        for (int e = 0; e < 8; ++e) qq[e] = (short)f2b(b2f((ushort)qq[e]) * SCALE_L2E);
        qf[t] = qq;
    }

    f32x4 O00 = {0.f,0.f,0.f,0.f}, O01 = {0.f,0.f,0.f,0.f};
    f32x4 O10 = {0.f,0.f,0.f,0.f}, O11 = {0.f,0.f,0.f,0.f};
    float lsum0[4] = {0.f,0.f,0.f,0.f};
    float lsum1[4] = {0.f,0.f,0.f,0.f};

    for (int cc = 0; cc < 7; ++cc) {
        __syncthreads();
        for (int u = tid; u < 448; u += 256) {
            const int key = u >> 2, d8 = (u & 3) * 8;
            const int n = cc * 112 + key;
            int i, j; nij(n, branch, i, j);
            const ushort* base = qkv + qkvB + (long long)((rowBase + i) * RES + colBase + j) * C3 + cbase + d8;
            bf16x8 kk = *(const bf16x8*)(base + 128);
            bf16x8 vv = *(const bf16x8*)(base + 256);
            *(bf16x8*)&ks[key * 40 + d8] = kk;
            #pragma unroll
            for (int e = 0; e < 8; ++e) vt[(d8 + e) * 136 + key] = (ushort)vv[e];
        }
        __syncthreads();

        #pragma unroll
        for (int p = 0; p < 4; ++p) {
            bf16x8 kf0 = *(const bf16x8*)&ks[(p * 32 + c16) * 40 + g * 8];
            bf16x8 kf1;
            if (p < 3) kf1 = *(const bf16x8*)&ks[(p * 32 + 16 + c16) * 40 + g * 8];
            bf16x8 vf0 = *(const bf16x8*)&vt[c16 * 136 + p * 32 + g * 8];
            bf16x8 vf1 = *(const bf16x8*)&vt[(16 + c16) * 136 + p * 32 + g * 8];
            ushort* pb = &pl[wv][0];

            #pragma unroll
            for (int t = 0; t < 2; ++t) if (t < nt) {
                const bf16x8 qq = t ? qf[1] : qf[0];
                f32x4 z = {0.f,0.f,0.f,0.f};
                f32x4 S0 = __builtin_amdgcn_mfma_f32_16x16x32_bf16(qq, kf0, z, 0, 0, 0);
                f32x4 S1 = z;
                if (p < 3) S1 = __builtin_amdgcn_mfma_f32_16x16x32_bf16(qq, kf1, z, 0, 0, 0);
                ushort pw0[4], pw1[4];
                #pragma unroll
                for (int r = 0; r < 4; ++r) {
                    float e0 = exp2f(S0[r]);
                    if (t) lsum1[r] += e0; else lsum0[r] += e0;
                    pw0[r] = f2b_t(e0);
                    if (p < 3) {
                        float e1 = exp2f(S1[r]);
                        if (t) lsum1[r] += e1; else lsum0[r] += e1;
                        pw1[r] = f2b_t(e1);
                    } else pw1[r] = 0;
                }
                #pragma unroll
                for (int r = 0; r < 4; ++r) {
                    pb[(g * 4 + r) * 40 + c16]      = pw0[r];
                    pb[(g * 4 + r) * 40 + 16 + c16] = pw1[r];
                }
                bf16x8 pf = *(const bf16x8*)&pb[c16 * 40 + g * 8];
                if (t) {
                    O10 = __builtin_amdgcn_mfma_f32_16x16x32_bf16(pf, vf0, O10, 0, 0, 0);
                    O11 = __builtin_amdgcn_mfma_f32_16x16x32_bf16(pf, vf1, O11, 0, 0, 0);
                } else {
                    O00 = __builtin_amdgcn_mfma_f32_16x16x32_bf16(pf, vf0, O00, 0, 0, 0);
                    O01 = __builtin_amdgcn_mfma_f32_16x16x32_bf16(pf, vf1, O01, 0, 0, 0);
                }
            }
        }
    }

    const int H_sp = branch ? 7 : RES;
    const int W_sp = branch ? RES : 7;
    #pragma unroll
    for (int t = 0; t < 2; ++t) if (t < nt) {
        float* ob = &ol[wv][0];
        #pragma unroll
        for (int r = 0; r < 4; ++r) {
            float s = t ? lsum1[r] : lsum0[r];
            s += __shfl_xor(s, 1); s += __shfl_xor(s, 2);
            s += __shfl_xor(s, 4); s += __shfl_xor(s, 8);
            const float inv = 1.f / s;
            const f32x4 Oa = t ? O10 : O00;
            const f32x4 Ob = t ? O11 : O01;
            ob[(g * 4 + r) * 36 + c16]      = Oa[r] * inv;
            ob[(g * 4 + r) * 36 + 16 + c16] = Ob[r] * inv;
        }
        const int r2 = lane >> 2, db = (lane & 3) * 8;
        const int n0 = (t0 + t) * 16 + r2;
        int i0, j0; nij(n0, branch, i0, j0);
        float acc[8];
        #pragma unroll
        for (int e = 0; e < 8; ++e) acc[e] = ob[r2 * 36 + db + e] + cb[head * 32 + db + e];
        #pragma unroll
        for (int dij = 0; dij < 9; ++dij) {
            const int di = dij / 3 - 1, dj = dij % 3 - 1;
            const int ii = i0 + di, jj = j0 + dj;
            if (ii >= 0 && ii < H_sp && jj >= 0 && jj < W_sp) {
                const ushort* vp = qkv + qkvB + (long long)((rowBase + ii) * RES + colBase + jj) * C3 + 256 + cbase + db;
                bf16x8 vv = *(const bf16x8*)vp;
                #pragma unroll
                for (int e = 0; e < 8; ++e)
                    acc[e] += cw[(head * 32 + db + e) * 9 + dij] * b2f((ushort)vv[e]);
            }
        }
        const long long Lq = (long long)(rowBase + i0) * RES + colBase + j0;
        ushort* op = att + ((long long)b * LTOK + Lq) * CDIM + cbase + db;
        bf16x8 ov;
        #pragma unroll
        for (int e = 0; e < 8; ++e) ov[e] = (short)f2b(acc[e]);
        *(bf16x8*)op = ov;
    }
}

// ---------------- K3: fused proj+resid+LN2+FC1+GELU+FC2+resid, weight-stationary (R14-proven) ----------------
__global__ __launch_bounds__(512) void k_pmlp(const ushort* __restrict__ att,
        const ushort* __restrict__ wproj_bf, const float* __restrict__ bproj,
        const float* __restrict__ x,
        const float* __restrict__ g2, const float* __restrict__ b2,
        const ushort* __restrict__ w1bf, const float* __restrict__ bfc1,
        const ushort* __restrict__ w2bf, const float* __restrict__ bfc2,
        float* __restrict__ out)
{
    __shared__ float  xs[32 * 132];
    __shared__ ushort ys[32 * 136];
    __shared__ ushort hs[32 * 520];
    const int tid = threadIdx.x;
    const int wv = tid >> 6, lane = tid & 63;
    const int c16 = lane & 15, g = lane >> 4;

    bf16x8 wpr[4];
    #pragma unroll
    for (int kc = 0; kc < 4; ++kc)
        wpr[kc] = *(const bf16x8*)&wproj_bf[(wv * 16 + c16) * CDIM + kc * 32 + g * 8];
    bf16x8 w1r[4][4];
    #pragma unroll
    for (int t = 0; t < 4; ++t)
        #pragma unroll
        for (int kc = 0; kc < 4; ++kc)
            w1r[t][kc] = *(const bf16x8*)&w1bf[(wv * 64 + t * 16 + c16) * CDIM + kc * 32 + g * 8];
    const float4 bpv = *(const float4*)&bproj[wv * 16 + g * 4];
    float4 b1v[4];
    #pragma unroll
    for (int t = 0; t < 4; ++t) b1v[t] = *(const float4*)&bfc1[wv * 64 + t * 16 + g * 4];
    const float4 b2v = *(const float4*)&bfc2[wv * 16 + g * 4];

    const int r = tid >> 4, l16 = tid & 15;
    float4 gv0 = *(const float4*)(g2 + l16 * 8);
    float4 gv4 = *(const float4*)(g2 + l16 * 8 + 4);
    float4 bv0 = *(const float4*)(b2 + l16 * 8);
    float4 bv4 = *(const float4*)(b2 + l16 * 8 + 4);

    for (int c = blockIdx.x; c < CHUNKS; c += GRID) {
        const long long row0 = (long long)c * 32;

        f32x4 resid[2];
        {
            bf16x8 ab[2][4];
            #pragma unroll
            for (int mt = 0; mt < 2; ++mt)
                #pragma unroll
                for (int kc = 0; kc < 4; ++kc)
                    ab[mt][kc] = *(const bf16x8*)&att[(row0 + mt * 16 + c16) * CDIM + kc * 32 + g * 8];
            const int col = wv * 16 + g * 4;
            #pragma unroll
            for (int mt = 0; mt < 2; ++mt) {
                f32x4 a = {0.f, 0.f, 0.f, 0.f};
                #pragma unroll
                for (int kc = 0; kc < 4; ++kc)
                    a = __builtin_amdgcn_mfma_f32_16x16x32_bf16(wpr[kc], ab[mt][kc], a, 0, 0, 0);
                float4 xv = *(const float4*)&x[(row0 + mt * 16 + c16) * CDIM + col];
                f32x4 rr;
                rr[0] = a[0] + xv.x + bpv.x;
                rr[1] = a[1] + xv.y + bpv.y;
                rr[2] = a[2] + xv.z + bpv.z;
                rr[3] = a[3] + xv.w + bpv.w;
                resid[mt] = rr;
                *(float4*)&xs[(mt * 16 + c16) * 132 + col] = make_float4(rr[0], rr[1], rr[2], rr[3]);
            }
        }
        __syncthreads();   // B1: xs ready

        {
            float4 a0 = *(const float4*)&xs[r * 132 + l16 * 8];
            float4 a1 = *(const float4*)&xs[r * 132 + l16 * 8 + 4];
            float s  = a0.x + a0.y + a0.z + a0.w + a1.x + a1.y + a1.z + a1.w;
            float s2 = a0.x*a0.x + a0.y*a0.y + a0.z*a0.z + a0.w*a0.w
                     + a1.x*a1.x + a1.y*a1.y + a1.z*a1.z + a1.w*a1.w;
            #pragma unroll
            for (int m = 8; m >= 1; m >>= 1) { s += __shfl_xor(s, m, 16); s2 += __shfl_xor(s2, m, 16); }
            const float mean = s * (1.f / 128.f);
            const float var = s2 * (1.f / 128.f) - mean * mean;
            const float rs = rsqrtf(var + 1e-5f);
            ushort4 w0, w1;
            w0.x = f2b((a0.x - mean) * rs * gv0.x + bv0.x);
            w0.y = f2b((a0.y - mean) * rs * gv0.y + bv0.y);
            w0.z = f2b((a0.z - mean) * rs * gv0.z + bv0.z);
            w0.w = f2b((a0.w - mean) * rs * gv0.w + bv0.w);
            w1.x = f2b((a1.x - mean) * rs * gv4.x + bv4.x);
            w1.y = f2b((a1.y - mean) * rs * gv4.y + bv4.y);
            w1.z = f2b((a1.z - mean) * rs * gv4.z + bv4.z);
            w1.w = f2b((a1.w - mean) * rs * gv4.w + bv4.w);
            *(ushort4*)&ys[r * 136 + l16 * 8]     = w0;
            *(ushort4*)&ys[r * 136 + l16 * 8 + 4] = w1;
        }
        __syncthreads();   // B2: ys ready

        bf16x8 yb[2][4];
        #pragma unroll
        for (int mt = 0; mt < 2; ++mt)
            #pragma unroll
            for (int kc = 0; kc < 4; ++kc)
                yb[mt][kc] = *(const bf16x8*)&ys[(mt * 16 + c16) * 136 + kc * 32 + g * 8];

        #pragma unroll
        for (int t = 0; t < 4; ++t) {
            #pragma unroll
            for (int mt = 0; mt < 2; ++mt) {
                f32x4 a = {0.f, 0.f, 0.f, 0.f};
                #pragma unroll
                for (int kc = 0; kc < 4; ++kc)
                    a = __builtin_amdgcn_mfma_f32_16x16x32_bf16(w1r[t][kc], yb[mt][kc], a, 0, 0, 0);
                ushort4 sv;
                sv.x = f2b(gelu_f(a[0] + b1v[t].x));
                sv.y = f2b(gelu_f(a[1] + b1v[t].y));
                sv.z = f2b(gelu_f(a[2] + b1v[t].z));
                sv.w = f2b(gelu_f(a[3] + b1v[t].w));
                *(ushort4*)&hs[(mt * 16 + c16) * 520 + wv * 64 + t * 16 + g * 4] = sv;
            }
        }

        bf16x8 w2r[16];
        #pragma unroll
        for (int kc = 0; kc < 16; ++kc)
            w2r[kc] = *(const bf16x8*)&w2bf[(wv * 16 + c16) * 512 + kc * 32 + g * 8];

        __syncthreads();   // B3: hs ready

        f32x4 acc2[2] = {{0.f,0.f,0.f,0.f},{0.f,0.f,0.f,0.f}};
        #pragma unroll
        for (int kc = 0; kc < 16; ++kc) {
            bf16x8 hb[2];
            #pragma unroll
            for (int mt = 0; mt < 2; ++mt)
                hb[mt] = *(const bf16x8*)&hs[(mt * 16 + c16) * 520 + kc * 32 + g * 8];
            #pragma unroll
            for (int mt = 0; mt < 2; ++mt)
                acc2[mt] = __builtin_amdgcn_mfma_f32_16x16x32_bf16(w2r[kc], hb[mt], acc2[mt], 0, 0, 0);
        }

        {
            const int col = wv * 16 + g * 4;
            #pragma unroll
            for (int mt = 0; mt < 2; ++mt) {
                const long long row = row0 + mt * 16 + c16;
                float4 o;
                o.x = acc2[mt][0] + resid[mt][0] + b2v.x;
                o.y = acc2[mt][1] + resid[mt][1] + b2v.y;
                o.z = acc2[mt][2] + resid[mt][2] + b2v.z;
                o.w = acc2[mt][3] + resid[mt][3] + b2v.w;
                *(float4*)&out[row * CDIM + col] = o;
            }
        }
    }
}

extern "C" void kernel_launch(void* const* d_in, const int* in_sizes, int n_in,
                              void* d_out, int out_size, void* d_ws, size_t ws_size,
                              hipStream_t stream) {
    const float* x     = (const float*)d_in[0];
    const float* g1    = (const float*)d_in[1];
    const float* b1    = (const float*)d_in[2];
    const float* wqkv  = (const float*)d_in[3];
    const float* cw0   = (const float*)d_in[4];
    const float* cb0   = (const float*)d_in[5];
    const float* cw1   = (const float*)d_in[6];
    const float* cb1   = (const float*)d_in[7];
    const float* wproj = (const float*)d_in[8];
    const float* bproj = (const float*)d_in[9];
    const float* g2    = (const float*)d_in[10];
    const float* b2    = (const float*)d_in[11];
    const float* wfc1  = (const float*)d_in[12];
    const float* bfc1  = (const float*)d_in[13];
    const float* wfc2  = (const float*)d_in[14];
    const float* bfc2  = (const float*)d_in[15];

    char* wsb = (char*)d_ws;
    ushort* qkv_bf   = (ushort*)wsb;                           // 19,267,584 B
    ushort* att_bf   = (ushort*)(wsb + 19267584);              //  6,422,528 B
    char*   wbase    = wsb + 19267584 + 6422528;
    ushort* wqkv_bf  = (ushort*)(wbase);
    ushort* wproj_bf = (ushort*)(wbase + 98304);
    ushort* wfc1_bf  = (ushort*)(wbase + 98304 + 32768);
    ushort* wfc2_bf  = (ushort*)(wbase + 98304 + 32768 + 131072);

    float* out = (float*)d_out;

    k_cvt<<<192, 256, 0, stream>>>(wqkv, wproj, wfc1, wfc2, wqkv_bf, wproj_bf, wfc1_bf, wfc2_bf);
    k_ln_qkv<<<GRID, 512, 0, stream>>>(x, g1, b1, wqkv_bf, qkv_bf);
    k_attn_mfma<<<dim3(128, 7), 256, 0, stream>>>(qkv_bf, cw0, cb0, cw1, cb1, att_bf);
    k_pmlp<<<GRID, 512, 0, stream>>>(att_bf, wproj_bf, bproj, x, g2, b2,
                                     wfc1_bf, bfc1, wfc2_bf, bfc2, out);
}

// Round 21
// 108.100 us; speedup vs baseline: 1.0381x; 1.0381x over previous
//
#include <hip/hip_runtime.h>
#include <cstdint>

#define LTOK 12544
#define BATCH 2
#define CDIM 128
#define C3 384
#define RES 112
#define NROWS (BATCH * LTOK)  // 25088
#define CHUNKS 784            // 32-row chunks
#define GRID 256
#define SCALE 0.17677669529663687f       // 1/sqrt(32)
#define SCALE_L2E 0.25505578188526813f   // SCALE * log2(e)

typedef __attribute__((ext_vector_type(8))) short bf16x8;
typedef __attribute__((ext_vector_type(4))) float f32x4;

__device__ inline ushort f2b(float f) {
    union { float f; unsigned u; } v; v.f = f;
    unsigned r = (v.u + 0x7FFFu + ((v.u >> 16) & 1u)) >> 16;
    return (ushort)r;
}
__device__ inline ushort f2b_t(float f) {   // truncating bf16 (P-pack only)
    union { float f; unsigned u; } v; v.f = f;
    return (ushort)(v.u >> 16);
}
__device__ inline float b2f(ushort u) {
    union { float f; unsigned u; } v; v.u = ((unsigned)u) << 16; return v.f;
}
// tanh-form GELU via hw exp
__device__ inline float gelu_f(float a) {
    float u2 = 1.5957691216f * (a + 0.044715f * a * a * a);
    return a - a / (__expf(u2) + 1.0f);
}

// map window-local token n -> (i, j); branch 0: W_sp=7, branch 1: W_sp=112
__device__ inline void nij(int n, int branch, int& i, int& j) {
    if (branch == 0) { i = n / 7; j = n - i * 7; }
    else             { i = n / 112; j = n - i * 112; }
}

// ---------------- K0: convert all weights to bf16 ----------------
__global__ __launch_bounds__(256) void k_cvt(const float* __restrict__ w0, const float* __restrict__ w1,
        const float* __restrict__ w2, const float* __restrict__ w3,
        ushort* __restrict__ o0, ushort* __restrict__ o1,
        ushort* __restrict__ o2, ushort* __restrict__ o3)
{
    int idx = blockIdx.x * 256 + threadIdx.x;  // vec4 index
    const float* src; ushort* dst; int vi;
    if      (idx < 12288) { src = w0; dst = o0; vi = idx; }
    else if (idx < 16384) { src = w1; dst = o1; vi = idx - 12288; }
    else if (idx < 32768) { src = w2; dst = o2; vi = idx - 16384; }
    else                  { src = w3; dst = o3; vi = idx - 32768; }
    float4 v = ((const float4*)src)[vi];
    ushort4 r; r.x = f2b(v.x); r.y = f2b(v.y); r.z = f2b(v.z); r.w = f2b(v.w);
    ((ushort4*)dst)[vi] = r;
}

// ---------------- K1: LN1 + QKV GEMM, weight-stationary grid-stride (R14-proven) ----------------
__global__ __launch_bounds__(512) void k_ln_qkv(const float* __restrict__ x,
        const float* __restrict__ g1, const float* __restrict__ b1,
        const ushort* __restrict__ wqkv_bf, ushort* __restrict__ qkv)
{
    __shared__ ushort ys[32 * 136];
    const int tid = threadIdx.x;
    const int wv = tid >> 6, lane = tid & 63;
    const int c16 = lane & 15, g = lane >> 4;

    bf16x8 wr[3][4];
    #pragma unroll
    for (int t = 0; t < 3; ++t)
        #pragma unroll
        for (int kc = 0; kc < 4; ++kc)
            wr[t][kc] = *(const bf16x8*)&wqkv_bf[(wv * 48 + t * 16 + c16) * CDIM + kc * 32 + g * 8];

    const int r = tid >> 4, l16 = tid & 15;
    float4 gv0 = *(const float4*)(g1 + l16 * 8);
    float4 gv4 = *(const float4*)(g1 + l16 * 8 + 4);
    float4 bv0 = *(const float4*)(b1 + l16 * 8);
    float4 bv4 = *(const float4*)(b1 + l16 * 8 + 4);

    for (int c = blockIdx.x; c < CHUNKS; c += GRID) {
        const long long row0 = (long long)c * 32;

        {
            const float* xr = x + (row0 + r) * CDIM + l16 * 8;
            float4 a0 = *(const float4*)xr;
            float4 a1 = *(const float4*)(xr + 4);
            float s  = a0.x + a0.y + a0.z + a0.w + a1.x + a1.y + a1.z + a1.w;
            float s2 = a0.x*a0.x + a0.y*a0.y + a0.z*a0.z + a0.w*a0.w
                     + a1.x*a1.x + a1.y*a1.y + a1.z*a1.z + a1.w*a1.w;
            #pragma unroll
            for (int m = 8; m >= 1; m >>= 1) { s += __shfl_xor(s, m, 16); s2 += __shfl_xor(s2, m, 16); }
            const float mean = s * (1.f / 128.f);
            const float var = s2 * (1.f / 128.f) - mean * mean;
            const float rs = rsqrtf(var + 1e-5f);
            ushort4 w0, w1;
            w0.x = f2b((a0.x - mean) * rs * gv0.x + bv0.x);
            w0.y = f2b((a0.y - mean) * rs * gv0.y + bv0.y);
            w0.z = f2b((a0.z - mean) * rs * gv0.z + bv0.z);
            w0.w = f2b((a0.w - mean) * rs * gv0.w + bv0.w);
            w1.x = f2b((a1.x - mean) * rs * gv4.x + bv4.x);
            w1.y = f2b((a1.y - mean) * rs * gv4.y + bv4.y);
            w1.z = f2b((a1.z - mean) * rs * gv4.z + bv4.z);
            w1.w = f2b((a1.w - mean) * rs * gv4.w + bv4.w);
            *(ushort4*)&ys[r * 136 + l16 * 8]     = w0;
            *(ushort4*)&ys[r * 136 + l16 * 8 + 4] = w1;
        }
        __syncthreads();   // B1: ys ready

        bf16x8 yb[2][4];
        #pragma unroll
        for (int mt = 0; mt < 2; ++mt)
            #pragma unroll
            for (int kc = 0; kc < 4; ++kc)
                yb[mt][kc] = *(const bf16x8*)&ys[(mt * 16 + c16) * 136 + kc * 32 + g * 8];
        __syncthreads();   // B2: all yb reads done

        #pragma unroll
        for (int t = 0; t < 3; ++t) {
            const int n0 = wv * 48 + t * 16;
            #pragma unroll
            for (int mt = 0; mt < 2; ++mt) {
                f32x4 acc = {0.f, 0.f, 0.f, 0.f};
                #pragma unroll
                for (int kc = 0; kc < 4; ++kc)
                    acc = __builtin_amdgcn_mfma_f32_16x16x32_bf16(wr[t][kc], yb[mt][kc], acc, 0, 0, 0);
                ushort4 sv;
                sv.x = f2b(acc[0]); sv.y = f2b(acc[1]); sv.z = f2b(acc[2]); sv.w = f2b(acc[3]);
                *(ushort4*)&qkv[(row0 + mt * 16 + c16) * C3 + n0 + g * 4] = sv;
            }
        }
    }
}

// ---------------- K2: windowed attention + LEPE via bf16 MFMA (R14 + hw exp2) ----------------
__global__ __launch_bounds__(256) void k_attn_mfma(const ushort* __restrict__ qkv,
        const float* __restrict__ cw0, const float* __restrict__ cb0,
        const float* __restrict__ cw1, const float* __restrict__ cb1,
        ushort* __restrict__ att)
{
    __shared__ __align__(16) ushort ks[112 * 40];
    __shared__ __align__(16) ushort vt[32 * 136];
    __shared__ __align__(16) ushort pl[4][16 * 40];
    __shared__ __align__(16) float  ol[4][16 * 36];

    const int tid = threadIdx.x;
    const int wv = tid >> 6, lane = tid & 63;
    const int g = lane >> 4, c16 = lane & 15;

    const int wh = blockIdx.x;
    const int branch = wh >> 6;
    const int idx = wh & 63;
    const int win = idx >> 1, head = idx & 1;
    const int b = win >> 4, w = win & 15;
    const int rowBase = branch ? w * 7 : 0;
    const int colBase = branch ? 0 : w * 7;
    const float* cw = branch ? cw1 : cw0;
    const float* cb = branch ? cb1 : cb0;
    const int cbase = branch * 64 + head * 32;
    const long long qkvB = (long long)b * LTOK * C3;

    {
        const int row = tid >> 3, cwd = tid & 7;
        *(unsigned*)&vt[row * 136 + 112 + cwd * 2] = 0u;
    }

    const int t0 = blockIdx.y * 7 + 2 * wv;
    const int nt = (2 * wv + 1 < 7) ? 2 : 1;

    // Q pre-scaled by (1/sqrt(d)) * log2(e): S is then in log2 domain, exp(s)=2^S
    bf16x8 qf[2];
    #pragma unroll
    for (int t = 0; t < 2; ++t) if (t < nt) {
        int n = (t0 + t) * 16 + c16;
        int i, j; nij(n, branch, i, j);
        const ushort* qp = qkv + qkvB + (long long)((rowBase + i) * RES + colBase + j) * C3 + cbase + g * 8;
        bf16x8 qq = *(const bf16x8*)qp;
        #pragma unroll
        for (int e = 0; e < 8; ++e) qq[e] = (short)f2b(b2f((ushort)qq[e]) * SCALE_L2E);
        qf[t] = qq;
    }

    f32x4 O00 = {0.f,0.f,0.f,0.f}, O01 = {0.f,0.f,0.f,0.f};
    f32x4 O10 = {0.f,0.f,0.f,0.f}, O11 = {0.f,0.f,0.f,0.f};
    float lsum0[4] = {0.f,0.f,0.f,0.f};
    float lsum1[4] = {0.f,0.f,0.f,0.f};

    for (int cc = 0; cc < 7; ++cc) {
        __syncthreads();
        for (int u = tid; u < 448; u += 256) {
            const int key = u >> 2, d8 = (u & 3) * 8;
            const int n = cc * 112 + key;
            int i, j; nij(n, branch, i, j);
            const ushort* base = qkv + qkvB + (long long)((rowBase + i) * RES + colBase + j) * C3 + cbase + d8;
            bf16x8 kk = *(const bf16x8*)(base + 128);
            bf16x8 vv = *(const bf16x8*)(base + 256);
            *(bf16x8*)&ks[key * 40 + d8] = kk;
            #pragma unroll
            for (int e = 0; e < 8; ++e) vt[(d8 + e) * 136 + key] = (ushort)vv[e];
        }
        __syncthreads();

        #pragma unroll
        for (int p = 0; p < 4; ++p) {
            bf16x8 kf0 = *(const bf16x8*)&ks[(p * 32 + c16) * 40 + g * 8];
            bf16x8 kf1;
            if (p < 3) kf1 = *(const bf16x8*)&ks[(p * 32 + 16 + c16) * 40 + g * 8];
            bf16x8 vf0 = *(const bf16x8*)&vt[c16 * 136 + p * 32 + g * 8];
            bf16x8 vf1 = *(const bf16x8*)&vt[(16 + c16) * 136 + p * 32 + g * 8];
            ushort* pb = &pl[wv][0];

            #pragma unroll
            for (int t = 0; t < 2; ++t) if (t < nt) {
                const bf16x8 qq = t ? qf[1] : qf[0];
                f32x4 z = {0.f,0.f,0.f,0.f};
                f32x4 S0 = __builtin_amdgcn_mfma_f32_16x16x32_bf16(qq, kf0, z, 0, 0, 0);
                f32x4 S1 = z;
                if (p < 3) S1 = __builtin_amdgcn_mfma_f32_16x16x32_bf16(qq, kf1, z, 0, 0, 0);
                ushort pw0[4], pw1[4];
                #pragma unroll
                for (int r = 0; r < 4; ++r) {
                    float e0 = __builtin_amdgcn_exp2f(S0[r]);   // bare v_exp_f32
                    if (t) lsum1[r] += e0; else lsum0[r] += e0;
                    pw0[r] = f2b_t(e0);
                    if (p < 3) {
                        float e1 = __builtin_amdgcn_exp2f(S1[r]);
                        if (t) lsum1[r] += e1; else lsum0[r] += e1;
                        pw1[r] = f2b_t(e1);
                    } else pw1[r] = 0;
                }
                #pragma unroll
                for (int r = 0; r < 4; ++r) {
                    pb[(g * 4 + r) * 40 + c16]      = pw0[r];
                    pb[(g * 4 + r) * 40 + 16 + c16] = pw1[r];
                }
                bf16x8 pf = *(const bf16x8*)&pb[c16 * 40 + g * 8];
                if (t) {
                    O10 = __builtin_amdgcn_mfma_f32_16x16x32_bf16(pf, vf0, O10, 0, 0, 0);
                    O11 = __builtin_amdgcn_mfma_f32_16x16x32_bf16(pf, vf1, O11, 0, 0, 0);
                } else {
                    O00 = __builtin_amdgcn_mfma_f32_16x16x32_bf16(pf, vf0, O00, 0, 0, 0);
                    O01 = __builtin_amdgcn_mfma_f32_16x16x32_bf16(pf, vf1, O01, 0, 0, 0);
                }
            }
        }
    }

    const int H_sp = branch ? 7 : RES;
    const int W_sp = branch ? RES : 7;
    #pragma unroll
    for (int t = 0; t < 2; ++t) if (t < nt) {
        float* ob = &ol[wv][0];
        #pragma unroll
        for (int r = 0; r < 4; ++r) {
            float s = t ? lsum1[r] : lsum0[r];
            s += __shfl_xor(s, 1); s += __shfl_xor(s, 2);
            s += __shfl_xor(s, 4); s += __shfl_xor(s, 8);
            const float inv = 1.f / s;
            const f32x4 Oa = t ? O10 : O00;
            const f32x4 Ob = t ? O11 : O01;
            ob[(g * 4 + r) * 36 + c16]      = Oa[r] * inv;
            ob[(g * 4 + r) * 36 + 16 + c16] = Ob[r] * inv;
        }
        const int r2 = lane >> 2, db = (lane & 3) * 8;
        const int n0 = (t0 + t) * 16 + r2;
        int i0, j0; nij(n0, branch, i0, j0);
        float acc[8];
        #pragma unroll
        for (int e = 0; e < 8; ++e) acc[e] = ob[r2 * 36 + db + e] + cb[head * 32 + db + e];
        #pragma unroll
        for (int dij = 0; dij < 9; ++dij) {
            const int di = dij / 3 - 1, dj = dij % 3 - 1;
            const int ii = i0 + di, jj = j0 + dj;
            if (ii >= 0 && ii < H_sp && jj >= 0 && jj < W_sp) {
                const ushort* vp = qkv + qkvB + (long long)((rowBase + ii) * RES + colBase + jj) * C3 + 256 + cbase + db;
                bf16x8 vv = *(const bf16x8*)vp;
                #pragma unroll
                for (int e = 0; e < 8; ++e)
                    acc[e] += cw[(head * 32 + db + e) * 9 + dij] * b2f((ushort)vv[e]);
            }
        }
        const long long Lq = (long long)(rowBase + i0) * RES + colBase + j0;
        ushort* op = att + ((long long)b * LTOK + Lq) * CDIM + cbase + db;
        bf16x8 ov;
        #pragma unroll
        for (int e = 0; e < 8; ++e) ov[e] = (short)f2b(acc[e]);
        *(bf16x8*)op = ov;
    }
}

// ---------------- K3: fused proj+resid+LN2+FC1+GELU+FC2+resid, weight-stationary (R14-proven) ----------------
__global__ __launch_bounds__(512) void k_pmlp(const ushort* __restrict__ att,
        const ushort* __restrict__ wproj_bf, const float* __restrict__ bproj,
        const float* __restrict__ x,
        const float* __restrict__ g2, const float* __restrict__ b2,
        const ushort* __restrict__ w1bf, const float* __restrict__ bfc1,
        const ushort* __restrict__ w2bf, const float* __restrict__ bfc2,
        float* __restrict__ out)
{
    __shared__ float  xs[32 * 132];
    __shared__ ushort ys[32 * 136];
    __shared__ ushort hs[32 * 520];
    const int tid = threadIdx.x;
    const int wv = tid >> 6, lane = tid & 63;
    const int c16 = lane & 15, g = lane >> 4;

    bf16x8 wpr[4];
    #pragma unroll
    for (int kc = 0; kc < 4; ++kc)
        wpr[kc] = *(const bf16x8*)&wproj_bf[(wv * 16 + c16) * CDIM + kc * 32 + g * 8];
    bf16x8 w1r[4][4];
    #pragma unroll
    for (int t = 0; t < 4; ++t)
        #pragma unroll
        for (int kc = 0; kc < 4; ++kc)
            w1r[t][kc] = *(const bf16x8*)&w1bf[(wv * 64 + t * 16 + c16) * CDIM + kc * 32 + g * 8];
    const float4 bpv = *(const float4*)&bproj[wv * 16 + g * 4];
    float4 b1v[4];
    #pragma unroll
    for (int t = 0; t < 4; ++t) b1v[t] = *(const float4*)&bfc1[wv * 64 + t * 16 + g * 4];
    const float4 b2v = *(const float4*)&bfc2[wv * 16 + g * 4];

    const int r = tid >> 4, l16 = tid & 15;
    float4 gv0 = *(const float4*)(g2 + l16 * 8);
    float4 gv4 = *(const float4*)(g2 + l16 * 8 + 4);
    float4 bv0 = *(const float4*)(b2 + l16 * 8);
    float4 bv4 = *(const float4*)(b2 + l16 * 8 + 4);

    for (int c = blockIdx.x; c < CHUNKS; c += GRID) {
        const long long row0 = (long long)c * 32;

        f32x4 resid[2];
        {
            bf16x8 ab[2][4];
            #pragma unroll
            for (int mt = 0; mt < 2; ++mt)
                #pragma unroll
                for (int kc = 0; kc < 4; ++kc)
                    ab[mt][kc] = *(const bf16x8*)&att[(row0 + mt * 16 + c16) * CDIM + kc * 32 + g * 8];
            const int col = wv * 16 + g * 4;
            #pragma unroll
            for (int mt = 0; mt < 2; ++mt) {
                f32x4 a = {0.f, 0.f, 0.f, 0.f};
                #pragma unroll
                for (int kc = 0; kc < 4; ++kc)
                    a = __builtin_amdgcn_mfma_f32_16x16x32_bf16(wpr[kc], ab[mt][kc], a, 0, 0, 0);
                float4 xv = *(const float4*)&x[(row0 + mt * 16 + c16) * CDIM + col];
                f32x4 rr;
                rr[0] = a[0] + xv.x + bpv.x;
                rr[1] = a[1] + xv.y + bpv.y;
                rr[2] = a[2] + xv.z + bpv.z;
                rr[3] = a[3] + xv.w + bpv.w;
                resid[mt] = rr;
                *(float4*)&xs[(mt * 16 + c16) * 132 + col] = make_float4(rr[0], rr[1], rr[2], rr[3]);
            }
        }
        __syncthreads();   // B1: xs ready

        {
            float4 a0 = *(const float4*)&xs[r * 132 + l16 * 8];
            float4 a1 = *(const float4*)&xs[r * 132 + l16 * 8 + 4];
            float s  = a0.x + a0.y + a0.z + a0.w + a1.x + a1.y + a1.z + a1.w;
            float s2 = a0.x*a0.x + a0.y*a0.y + a0.z*a0.z + a0.w*a0.w
                     + a1.x*a1.x + a1.y*a1.y + a1.z*a1.z + a1.w*a1.w;
            #pragma unroll
            for (int m = 8; m >= 1; m >>= 1) { s += __shfl_xor(s, m, 16); s2 += __shfl_xor(s2, m, 16); }
            const float mean = s * (1.f / 128.f);
            const float var = s2 * (1.f / 128.f) - mean * mean;
            const float rs = rsqrtf(var + 1e-5f);
            ushort4 w0, w1;
            w0.x = f2b((a0.x - mean) * rs * gv0.x + bv0.x);
            w0.y = f2b((a0.y - mean) * rs * gv0.y + bv0.y);
            w0.z = f2b((a0.z - mean) * rs * gv0.z + bv0.z);
            w0.w = f2b((a0.w - mean) * rs * gv0.w + bv0.w);
            w1.x = f2b((a1.x - mean) * rs * gv4.x + bv4.x);
            w1.y = f2b((a1.y - mean) * rs * gv4.y + bv4.y);
            w1.z = f2b((a1.z - mean) * rs * gv4.z + bv4.z);
            w1.w = f2b((a1.w - mean) * rs * gv4.w + bv4.w);
            *(ushort4*)&ys[r * 136 + l16 * 8]     = w0;
            *(ushort4*)&ys[r * 136 + l16 * 8 + 4] = w1;
        }
        __syncthreads();   // B2: ys ready

        bf16x8 yb[2][4];
        #pragma unroll
        for (int mt = 0; mt < 2; ++mt)
            #pragma unroll
            for (int kc = 0; kc < 4; ++kc)
                yb[mt][kc] = *(const bf16x8*)&ys[(mt * 16 + c16) * 136 + kc * 32 + g * 8];

        #pragma unroll
        for (int t = 0; t < 4; ++t) {
            #pragma unroll
            for (int mt = 0; mt < 2; ++mt) {
                f32x4 a = {0.f, 0.f, 0.f, 0.f};
                #pragma unroll
                for (int kc = 0; kc < 4; ++kc)
                    a = __builtin_amdgcn_mfma_f32_16x16x32_bf16(w1r[t][kc], yb[mt][kc], a, 0, 0, 0);
                ushort4 sv;
                sv.x = f2b(gelu_f(a[0] + b1v[t].x));
                sv.y = f2b(gelu_f(a[1] + b1v[t].y));
                sv.z = f2b(gelu_f(a[2] + b1v[t].z));
                sv.w = f2b(gelu_f(a[3] + b1v[t].w));
                *(ushort4*)&hs[(mt * 16 + c16) * 520 + wv * 64 + t * 16 + g * 4] = sv;
            }
        }

        bf16x8 w2r[16];
        #pragma unroll
        for (int kc = 0; kc < 16; ++kc)
            w2r[kc] = *(const bf16x8*)&w2bf[(wv * 16 + c16) * 512 + kc * 32 + g * 8];

        __syncthreads();   // B3: hs ready

        f32x4 acc2[2] = {{0.f,0.f,0.f,0.f},{0.f,0.f,0.f,0.f}};
        #pragma unroll
        for (int kc = 0; kc < 16; ++kc) {
            bf16x8 hb[2];
            #pragma unroll
            for (int mt = 0; mt < 2; ++mt)
                hb[mt] = *(const bf16x8*)&hs[(mt * 16 + c16) * 520 + kc * 32 + g * 8];
            #pragma unroll
            for (int mt = 0; mt < 2; ++mt)
                acc2[mt] = __builtin_amdgcn_mfma_f32_16x16x32_bf16(w2r[kc], hb[mt], acc2[mt], 0, 0, 0);
        }

        {
            const int col = wv * 16 + g * 4;
            #pragma unroll
            for (int mt = 0; mt < 2; ++mt) {
                const long long row = row0 + mt * 16 + c16;
                float4 o;
                o.x = acc2[mt][0] + resid[mt][0] + b2v.x;
                o.y = acc2[mt][1] + resid[mt][1] + b2v.y;
                o.z = acc2[mt][2] + resid[mt][2] + b2v.z;
                o.w = acc2[mt][3] + resid[mt][3] + b2v.w;
                *(float4*)&out[row * CDIM + col] = o;
            }
        }
    }
}

extern "C" void kernel_launch(void* const* d_in, const int* in_sizes, int n_in,
                              void* d_out, int out_size, void* d_ws, size_t ws_size,
                              hipStream_t stream) {
    const float* x     = (const float*)d_in[0];
    const float* g1    = (const float*)d_in[1];
    const float* b1    = (const float*)d_in[2];
    const float* wqkv  = (const float*)d_in[3];
    const float* cw0   = (const float*)d_in[4];
    const float* cb0   = (const float*)d_in[5];
    const float* cw1   = (const float*)d_in[6];
    const float* cb1   = (const float*)d_in[7];
    const float* wproj = (const float*)d_in[8];
    const float* bproj = (const float*)d_in[9];
    const float* g2    = (const float*)d_in[10];
    const float* b2    = (const float*)d_in[11];
    const float* wfc1  = (const float*)d_in[12];
    const float* bfc1  = (const float*)d_in[13];
    const float* wfc2  = (const float*)d_in[14];
    const float* bfc2  = (const float*)d_in[15];

    char* wsb = (char*)d_ws;
    ushort* qkv_bf   = (ushort*)wsb;                           // 19,267,584 B
    ushort* att_bf   = (ushort*)(wsb + 19267584);              //  6,422,528 B
    char*   wbase    = wsb + 19267584 + 6422528;
    ushort* wqkv_bf  = (ushort*)(wbase);
    ushort* wproj_bf = (ushort*)(wbase + 98304);
    ushort* wfc1_bf  = (ushort*)(wbase + 98304 + 32768);
    ushort* wfc2_bf  = (ushort*)(wbase + 98304 + 32768 + 131072);

    float* out = (float*)d_out;

    k_cvt<<<192, 256, 0, stream>>>(wqkv, wproj, wfc1, wfc2, wqkv_bf, wproj_bf, wfc1_bf, wfc2_bf);
    k_ln_qkv<<<GRID, 512, 0, stream>>>(x, g1, b1, wqkv_bf, qkv_bf);
    k_attn_mfma<<<dim3(128, 7), 256, 0, stream>>>(qkv_bf, cw0, cb0, cw1, cb1, att_bf);
    k_pmlp<<<GRID, 512, 0, stream>>>(att_bf, wproj_bf, bproj, x, g2, b2,
                                     wfc1_bf, bfc1, wfc2_bf, bfc2, out);
}

// Round 22
// 107.790 us; speedup vs baseline: 1.0410x; 1.0029x over previous
//
#include <hip/hip_runtime.h>
#include <cstdint>

#define LTOK 12544
#define BATCH 2
#define CDIM 128
#define C3 384
#define RES 112
#define NROWS (BATCH * LTOK)  // 25088
#define CHUNKS 784            // 32-row chunks
#define GRID 256
#define SCALE 0.17677669529663687f       // 1/sqrt(32)
#define SCALE_L2E 0.25505578188526813f   // SCALE * log2(e)

typedef __attribute__((ext_vector_type(8))) short bf16x8;
typedef __attribute__((ext_vector_type(4))) float f32x4;

__device__ inline ushort f2b(float f) {
    union { float f; unsigned u; } v; v.f = f;
    unsigned r = (v.u + 0x7FFFu + ((v.u >> 16) & 1u)) >> 16;
    return (ushort)r;
}
__device__ inline ushort f2b_t(float f) {   // truncating bf16 (P-pack only)
    union { float f; unsigned u; } v; v.f = f;
    return (ushort)(v.u >> 16);
}
__device__ inline float b2f(ushort u) {
    union { float f; unsigned u; } v; v.u = ((unsigned)u) << 16; return v.f;
}
// tanh-form GELU via bare v_exp_f32 (2^x): 1.5957691216*log2(e) = 2.3022083
__device__ inline float gelu_f(float a) {
    float u2 = 2.3022083f * (a + 0.044715f * a * a * a);
    return a - a / (__builtin_amdgcn_exp2f(u2) + 1.0f);
}

// map window-local token n -> (i, j); branch 0: W_sp=7, branch 1: W_sp=112
__device__ inline void nij(int n, int branch, int& i, int& j) {
    if (branch == 0) { i = n / 7; j = n - i * 7; }
    else             { i = n / 112; j = n - i * 112; }
}

// ---------------- K0: convert all weights to bf16 ----------------
__global__ __launch_bounds__(256) void k_cvt(const float* __restrict__ w0, const float* __restrict__ w1,
        const float* __restrict__ w2, const float* __restrict__ w3,
        ushort* __restrict__ o0, ushort* __restrict__ o1,
        ushort* __restrict__ o2, ushort* __restrict__ o3)
{
    int idx = blockIdx.x * 256 + threadIdx.x;  // vec4 index
    const float* src; ushort* dst; int vi;
    if      (idx < 12288) { src = w0; dst = o0; vi = idx; }
    else if (idx < 16384) { src = w1; dst = o1; vi = idx - 12288; }
    else if (idx < 32768) { src = w2; dst = o2; vi = idx - 16384; }
    else                  { src = w3; dst = o3; vi = idx - 32768; }
    float4 v = ((const float4*)src)[vi];
    ushort4 r; r.x = f2b(v.x); r.y = f2b(v.y); r.z = f2b(v.z); r.w = f2b(v.w);
    ((ushort4*)dst)[vi] = r;
}

// ---------------- K1: LN1 + QKV GEMM, weight-stationary grid-stride (R14-proven) ----------------
__global__ __launch_bounds__(512) void k_ln_qkv(const float* __restrict__ x,
        const float* __restrict__ g1, const float* __restrict__ b1,
        const ushort* __restrict__ wqkv_bf, ushort* __restrict__ qkv)
{
    __shared__ ushort ys[32 * 136];
    const int tid = threadIdx.x;
    const int wv = tid >> 6, lane = tid & 63;
    const int c16 = lane & 15, g = lane >> 4;

    bf16x8 wr[3][4];
    #pragma unroll
    for (int t = 0; t < 3; ++t)
        #pragma unroll
        for (int kc = 0; kc < 4; ++kc)
            wr[t][kc] = *(const bf16x8*)&wqkv_bf[(wv * 48 + t * 16 + c16) * CDIM + kc * 32 + g * 8];

    const int r = tid >> 4, l16 = tid & 15;
    float4 gv0 = *(const float4*)(g1 + l16 * 8);
    float4 gv4 = *(const float4*)(g1 + l16 * 8 + 4);
    float4 bv0 = *(const float4*)(b1 + l16 * 8);
    float4 bv4 = *(const float4*)(b1 + l16 * 8 + 4);

    for (int c = blockIdx.x; c < CHUNKS; c += GRID) {
        const long long row0 = (long long)c * 32;

        {
            const float* xr = x + (row0 + r) * CDIM + l16 * 8;
            float4 a0 = *(const float4*)xr;
            float4 a1 = *(const float4*)(xr + 4);
            float s  = a0.x + a0.y + a0.z + a0.w + a1.x + a1.y + a1.z + a1.w;
            float s2 = a0.x*a0.x + a0.y*a0.y + a0.z*a0.z + a0.w*a0.w
                     + a1.x*a1.x + a1.y*a1.y + a1.z*a1.z + a1.w*a1.w;
            #pragma unroll
            for (int m = 8; m >= 1; m >>= 1) { s += __shfl_xor(s, m, 16); s2 += __shfl_xor(s2, m, 16); }
            const float mean = s * (1.f / 128.f);
            const float var = s2 * (1.f / 128.f) - mean * mean;
            const float rs = rsqrtf(var + 1e-5f);
            ushort4 w0, w1;
            w0.x = f2b((a0.x - mean) * rs * gv0.x + bv0.x);
            w0.y = f2b((a0.y - mean) * rs * gv0.y + bv0.y);
            w0.z = f2b((a0.z - mean) * rs * gv0.z + bv0.z);
            w0.w = f2b((a0.w - mean) * rs * gv0.w + bv0.w);
            w1.x = f2b((a1.x - mean) * rs * gv4.x + bv4.x);
            w1.y = f2b((a1.y - mean) * rs * gv4.y + bv4.y);
            w1.z = f2b((a1.z - mean) * rs * gv4.z + bv4.z);
            w1.w = f2b((a1.w - mean) * rs * gv4.w + bv4.w);
            *(ushort4*)&ys[r * 136 + l16 * 8]     = w0;
            *(ushort4*)&ys[r * 136 + l16 * 8 + 4] = w1;
        }
        __syncthreads();   // B1: ys ready

        bf16x8 yb[2][4];
        #pragma unroll
        for (int mt = 0; mt < 2; ++mt)
            #pragma unroll
            for (int kc = 0; kc < 4; ++kc)
                yb[mt][kc] = *(const bf16x8*)&ys[(mt * 16 + c16) * 136 + kc * 32 + g * 8];
        __syncthreads();   // B2: all yb reads done

        #pragma unroll
        for (int t = 0; t < 3; ++t) {
            const int n0 = wv * 48 + t * 16;
            #pragma unroll
            for (int mt = 0; mt < 2; ++mt) {
                f32x4 acc = {0.f, 0.f, 0.f, 0.f};
                #pragma unroll
                for (int kc = 0; kc < 4; ++kc)
                    acc = __builtin_amdgcn_mfma_f32_16x16x32_bf16(wr[t][kc], yb[mt][kc], acc, 0, 0, 0);
                ushort4 sv;
                sv.x = f2b(acc[0]); sv.y = f2b(acc[1]); sv.z = f2b(acc[2]); sv.w = f2b(acc[3]);
                *(ushort4*)&qkv[(row0 + mt * 16 + c16) * C3 + n0 + g * 4] = sv;
            }
        }
    }
}

// ---------------- K2: windowed attention + LEPE via bf16 MFMA (R21-proven) ----------------
__global__ __launch_bounds__(256) void k_attn_mfma(const ushort* __restrict__ qkv,
        const float* __restrict__ cw0, const float* __restrict__ cb0,
        const float* __restrict__ cw1, const float* __restrict__ cb1,
        ushort* __restrict__ att)
{
    __shared__ __align__(16) ushort ks[112 * 40];
    __shared__ __align__(16) ushort vt[32 * 136];
    __shared__ __align__(16) ushort pl[4][16 * 40];
    __shared__ __align__(16) float  ol[4][16 * 36];

    const int tid = threadIdx.x;
    const int wv = tid >> 6, lane = tid & 63;
    const int g = lane >> 4, c16 = lane & 15;

    const int wh = blockIdx.x;
    const int branch = wh >> 6;
    const int idx = wh & 63;
    const int win = idx >> 1, head = idx & 1;
    const int b = win >> 4, w = win & 15;
    const int rowBase = branch ? w * 7 : 0;
    const int colBase = branch ? 0 : w * 7;
    const float* cw = branch ? cw1 : cw0;
    const float* cb = branch ? cb1 : cb0;
    const int cbase = branch * 64 + head * 32;
    const long long qkvB = (long long)b * LTOK * C3;

    {
        const int row = tid >> 3, cwd = tid & 7;
        *(unsigned*)&vt[row * 136 + 112 + cwd * 2] = 0u;
    }

    const int t0 = blockIdx.y * 7 + 2 * wv;
    const int nt = (2 * wv + 1 < 7) ? 2 : 1;

    // Q pre-scaled by (1/sqrt(d)) * log2(e): S is then in log2 domain, exp(s)=2^S
    bf16x8 qf[2];
    #pragma unroll
    for (int t = 0; t < 2; ++t) if (t < nt) {
        int n = (t0 + t) * 16 + c16;
        int i, j; nij(n, branch, i, j);
        const ushort* qp = qkv + qkvB + (long long)((rowBase + i) * RES + colBase + j) * C3 + cbase + g * 8;
        bf16x8 qq = *(const bf16x8*)qp;
        #pragma unroll
        for (int e = 0; e < 8; ++e) qq[e] = (short)f2b(b2f((ushort)qq[e]) * SCALE_L2E);
        qf[t] = qq;
    }

    f32x4 O00 = {0.f,0.f,0.f,0.f}, O01 = {0.f,0.f,0.f,0.f};
    f32x4 O10 = {0.f,0.f,0.f,0.f}, O11 = {0.f,0.f,0.f,0.f};
    float lsum0[4] = {0.f,0.f,0.f,0.f};
    float lsum1[4] = {0.f,0.f,0.f,0.f};

    for (int cc = 0; cc < 7; ++cc) {
        __syncthreads();
        for (int u = tid; u < 448; u += 256) {
            const int key = u >> 2, d8 = (u & 3) * 8;
            const int n = cc * 112 + key;
            int i, j; nij(n, branch, i, j);
            const ushort* base = qkv + qkvB + (long long)((rowBase + i) * RES + colBase + j) * C3 + cbase + d8;
            bf16x8 kk = *(const bf16x8*)(base + 128);
            bf16x8 vv = *(const bf16x8*)(base + 256);
            *(bf16x8*)&ks[key * 40 + d8] = kk;
            #pragma unroll
            for (int e = 0; e < 8; ++e) vt[(d8 + e) * 136 + key] = (ushort)vv[e];
        }
        __syncthreads();

        #pragma unroll
        for (int p = 0; p < 4; ++p) {
            bf16x8 kf0 = *(const bf16x8*)&ks[(p * 32 + c16) * 40 + g * 8];
            bf16x8 kf1;
            if (p < 3) kf1 = *(const bf16x8*)&ks[(p * 32 + 16 + c16) * 40 + g * 8];
            bf16x8 vf0 = *(const bf16x8*)&vt[c16 * 136 + p * 32 + g * 8];
            bf16x8 vf1 = *(const bf16x8*)&vt[(16 + c16) * 136 + p * 32 + g * 8];
            ushort* pb = &pl[wv][0];

            #pragma unroll
            for (int t = 0; t < 2; ++t) if (t < nt) {
                const bf16x8 qq = t ? qf[1] : qf[0];
                f32x4 z = {0.f,0.f,0.f,0.f};
                f32x4 S0 = __builtin_amdgcn_mfma_f32_16x16x32_bf16(qq, kf0, z, 0, 0, 0);
                f32x4 S1 = z;
                if (p < 3) S1 = __builtin_amdgcn_mfma_f32_16x16x32_bf16(qq, kf1, z, 0, 0, 0);
                ushort pw0[4], pw1[4];
                #pragma unroll
                for (int r = 0; r < 4; ++r) {
                    float e0 = __builtin_amdgcn_exp2f(S0[r]);   // bare v_exp_f32
                    if (t) lsum1[r] += e0; else lsum0[r] += e0;
                    pw0[r] = f2b_t(e0);
                    if (p < 3) {
                        float e1 = __builtin_amdgcn_exp2f(S1[r]);
                        if (t) lsum1[r] += e1; else lsum0[r] += e1;
                        pw1[r] = f2b_t(e1);
                    } else pw1[r] = 0;
                }
                #pragma unroll
                for (int r = 0; r < 4; ++r) {
                    pb[(g * 4 + r) * 40 + c16]      = pw0[r];
                    pb[(g * 4 + r) * 40 + 16 + c16] = pw1[r];
                }
                bf16x8 pf = *(const bf16x8*)&pb[c16 * 40 + g * 8];
                if (t) {
                    O10 = __builtin_amdgcn_mfma_f32_16x16x32_bf16(pf, vf0, O10, 0, 0, 0);
                    O11 = __builtin_amdgcn_mfma_f32_16x16x32_bf16(pf, vf1, O11, 0, 0, 0);
                } else {
                    O00 = __builtin_amdgcn_mfma_f32_16x16x32_bf16(pf, vf0, O00, 0, 0, 0);
                    O01 = __builtin_amdgcn_mfma_f32_16x16x32_bf16(pf, vf1, O01, 0, 0, 0);
                }
            }
        }
    }

    const int H_sp = branch ? 7 : RES;
    const int W_sp = branch ? RES : 7;
    #pragma unroll
    for (int t = 0; t < 2; ++t) if (t < nt) {
        float* ob = &ol[wv][0];
        #pragma unroll
        for (int r = 0; r < 4; ++r) {
            float s = t ? lsum1[r] : lsum0[r];
            s += __shfl_xor(s, 1); s += __shfl_xor(s, 2);
            s += __shfl_xor(s, 4); s += __shfl_xor(s, 8);
            const float inv = 1.f / s;
            const f32x4 Oa = t ? O10 : O00;
            const f32x4 Ob = t ? O11 : O01;
            ob[(g * 4 + r) * 36 + c16]      = Oa[r] * inv;
            ob[(g * 4 + r) * 36 + 16 + c16] = Ob[r] * inv;
        }
        const int r2 = lane >> 2, db = (lane & 3) * 8;
        const int n0 = (t0 + t) * 16 + r2;
        int i0, j0; nij(n0, branch, i0, j0);
        float acc[8];
        #pragma unroll
        for (int e = 0; e < 8; ++e) acc[e] = ob[r2 * 36 + db + e] + cb[head * 32 + db + e];
        #pragma unroll
        for (int dij = 0; dij < 9; ++dij) {
            const int di = dij / 3 - 1, dj = dij % 3 - 1;
            const int ii = i0 + di, jj = j0 + dj;
            if (ii >= 0 && ii < H_sp && jj >= 0 && jj < W_sp) {
                const ushort* vp = qkv + qkvB + (long long)((rowBase + ii) * RES + colBase + jj) * C3 + 256 + cbase + db;
                bf16x8 vv = *(const bf16x8*)vp;
                #pragma unroll
                for (int e = 0; e < 8; ++e)
                    acc[e] += cw[(head * 32 + db + e) * 9 + dij] * b2f((ushort)vv[e]);
            }
        }
        const long long Lq = (long long)(rowBase + i0) * RES + colBase + j0;
        ushort* op = att + ((long long)b * LTOK + Lq) * CDIM + cbase + db;
        bf16x8 ov;
        #pragma unroll
        for (int e = 0; e < 8; ++e) ov[e] = (short)f2b(acc[e]);
        *(bf16x8*)op = ov;
    }
}

// ---------------- K3: fused proj+resid+LN2+FC1+GELU+FC2+resid, weight-stationary (R14-proven) ----------------
__global__ __launch_bounds__(512) void k_pmlp(const ushort* __restrict__ att,
        const ushort* __restrict__ wproj_bf, const float* __restrict__ bproj,
        const float* __restrict__ x,
        const float* __restrict__ g2, const float* __restrict__ b2,
        const ushort* __restrict__ w1bf, const float* __restrict__ bfc1,
        const ushort* __restrict__ w2bf, const float* __restrict__ bfc2,
        float* __restrict__ out)
{
    __shared__ float  xs[32 * 132];
    __shared__ ushort ys[32 * 136];
    __shared__ ushort hs[32 * 520];
    const int tid = threadIdx.x;
    const int wv = tid >> 6, lane = tid & 63;
    const int c16 = lane & 15, g = lane >> 4;

    bf16x8 wpr[4];
    #pragma unroll
    for (int kc = 0; kc < 4; ++kc)
        wpr[kc] = *(const bf16x8*)&wproj_bf[(wv * 16 + c16) * CDIM + kc * 32 + g * 8];
    bf16x8 w1r[4][4];
    #pragma unroll
    for (int t = 0; t < 4; ++t)
        #pragma unroll
        for (int kc = 0; kc < 4; ++kc)
            w1r[t][kc] = *(const bf16x8*)&w1bf[(wv * 64 + t * 16 + c16) * CDIM + kc * 32 + g * 8];
    const float4 bpv = *(const float4*)&bproj[wv * 16 + g * 4];
    float4 b1v[4];
    #pragma unroll
    for (int t = 0; t < 4; ++t) b1v[t] = *(const float4*)&bfc1[wv * 64 + t * 16 + g * 4];
    const float4 b2v = *(const float4*)&bfc2[wv * 16 + g * 4];

    const int r = tid >> 4, l16 = tid & 15;
    float4 gv0 = *(const float4*)(g2 + l16 * 8);
    float4 gv4 = *(const float4*)(g2 + l16 * 8 + 4);
    float4 bv0 = *(const float4*)(b2 + l16 * 8);
    float4 bv4 = *(const float4*)(b2 + l16 * 8 + 4);

    for (int c = blockIdx.x; c < CHUNKS; c += GRID) {
        const long long row0 = (long long)c * 32;

        f32x4 resid[2];
        {
            bf16x8 ab[2][4];
            #pragma unroll
            for (int mt = 0; mt < 2; ++mt)
                #pragma unroll
                for (int kc = 0; kc < 4; ++kc)
                    ab[mt][kc] = *(const bf16x8*)&att[(row0 + mt * 16 + c16) * CDIM + kc * 32 + g * 8];
            const int col = wv * 16 + g * 4;
            #pragma unroll
            for (int mt = 0; mt < 2; ++mt) {
                f32x4 a = {0.f, 0.f, 0.f, 0.f};
                #pragma unroll
                for (int kc = 0; kc < 4; ++kc)
                    a = __builtin_amdgcn_mfma_f32_16x16x32_bf16(wpr[kc], ab[mt][kc], a, 0, 0, 0);
                float4 xv = *(const float4*)&x[(row0 + mt * 16 + c16) * CDIM + col];
                f32x4 rr;
                rr[0] = a[0] + xv.x + bpv.x;
                rr[1] = a[1] + xv.y + bpv.y;
                rr[2] = a[2] + xv.z + bpv.z;
                rr[3] = a[3] + xv.w + bpv.w;
                resid[mt] = rr;
                *(float4*)&xs[(mt * 16 + c16) * 132 + col] = make_float4(rr[0], rr[1], rr[2], rr[3]);
            }
        }
        __syncthreads();   // B1: xs ready

        {
            float4 a0 = *(const float4*)&xs[r * 132 + l16 * 8];
            float4 a1 = *(const float4*)&xs[r * 132 + l16 * 8 + 4];
            float s  = a0.x + a0.y + a0.z + a0.w + a1.x + a1.y + a1.z + a1.w;
            float s2 = a0.x*a0.x + a0.y*a0.y + a0.z*a0.z + a0.w*a0.w
                     + a1.x*a1.x + a1.y*a1.y + a1.z*a1.z + a1.w*a1.w;
            #pragma unroll
            for (int m = 8; m >= 1; m >>= 1) { s += __shfl_xor(s, m, 16); s2 += __shfl_xor(s2, m, 16); }
            const float mean = s * (1.f / 128.f);
            const float var = s2 * (1.f / 128.f) - mean * mean;
            const float rs = rsqrtf(var + 1e-5f);
            ushort4 w0, w1;
            w0.x = f2b((a0.x - mean) * rs * gv0.x + bv0.x);
            w0.y = f2b((a0.y - mean) * rs * gv0.y + bv0.y);
            w0.z = f2b((a0.z - mean) * rs * gv0.z + bv0.z);
            w0.w = f2b((a0.w - mean) * rs * gv0.w + bv0.w);
            w1.x = f2b((a1.x - mean) * rs * gv4.x + bv4.x);
            w1.y = f2b((a1.y - mean) * rs * gv4.y + bv4.y);
            w1.z = f2b((a1.z - mean) * rs * gv4.z + bv4.z);
            w1.w = f2b((a1.w - mean) * rs * gv4.w + bv4.w);
            *(ushort4*)&ys[r * 136 + l16 * 8]     = w0;
            *(ushort4*)&ys[r * 136 + l16 * 8 + 4] = w1;
        }
        __syncthreads();   // B2: ys ready

        bf16x8 yb[2][4];
        #pragma unroll
        for (int mt = 0; mt < 2; ++mt)
            #pragma unroll
            for (int kc = 0; kc < 4; ++kc)
                yb[mt][kc] = *(const bf16x8*)&ys[(mt * 16 + c16) * 136 + kc * 32 + g * 8];

        #pragma unroll
        for (int t = 0; t < 4; ++t) {
            #pragma unroll
            for (int mt = 0; mt < 2; ++mt) {
                f32x4 a = {0.f, 0.f, 0.f, 0.f};
                #pragma unroll
                for (int kc = 0; kc < 4; ++kc)
                    a = __builtin_amdgcn_mfma_f32_16x16x32_bf16(w1r[t][kc], yb[mt][kc], a, 0, 0, 0);
                ushort4 sv;
                sv.x = f2b(gelu_f(a[0] + b1v[t].x));
                sv.y = f2b(gelu_f(a[1] + b1v[t].y));
                sv.z = f2b(gelu_f(a[2] + b1v[t].z));
                sv.w = f2b(gelu_f(a[3] + b1v[t].w));
                *(ushort4*)&hs[(mt * 16 + c16) * 520 + wv * 64 + t * 16 + g * 4] = sv;
            }
        }

        bf16x8 w2r[16];
        #pragma unroll
        for (int kc = 0; kc < 16; ++kc)
            w2r[kc] = *(const bf16x8*)&w2bf[(wv * 16 + c16) * 512 + kc * 32 + g * 8];

        __syncthreads();   // B3: hs ready

        f32x4 acc2[2] = {{0.f,0.f,0.f,0.f},{0.f,0.f,0.f,0.f}};
        #pragma unroll
        for (int kc = 0; kc < 16; ++kc) {
            bf16x8 hb[2];
            #pragma unroll
            for (int mt = 0; mt < 2; ++mt)
                hb[mt] = *(const bf16x8*)&hs[(mt * 16 + c16) * 520 + kc * 32 + g * 8];
            #pragma unroll
            for (int mt = 0; mt < 2; ++mt)
                acc2[mt] = __builtin_amdgcn_mfma_f32_16x16x32_bf16(w2r[kc], hb[mt], acc2[mt], 0, 0, 0);
        }

        {
            const int col = wv * 16 + g * 4;
            #pragma unroll
            for (int mt = 0; mt < 2; ++mt) {
                const long long row = row0 + mt * 16 + c16;
                float4 o;
                o.x = acc2[mt][0] + resid[mt][0] + b2v.x;
                o.y = acc2[mt][1] + resid[mt][1] + b2v.y;
                o.z = acc2[mt][2] + resid[mt][2] + b2v.z;
                o.w = acc2[mt][3] + resid[mt][3] + b2v.w;
                *(float4*)&out[row * CDIM + col] = o;
            }
        }
    }
}

extern "C" void kernel_launch(void* const* d_in, const int* in_sizes, int n_in,
                              void* d_out, int out_size, void* d_ws, size_t ws_size,
                              hipStream_t stream) {
    const float* x     = (const float*)d_in[0];
    const float* g1    = (const float*)d_in[1];
    const float* b1    = (const float*)d_in[2];
    const float* wqkv  = (const float*)d_in[3];
    const float* cw0   = (const float*)d_in[4];
    const float* cb0   = (const float*)d_in[5];
    const float* cw1   = (const float*)d_in[6];
    const float* cb1   = (const float*)d_in[7];
    const float* wproj = (const float*)d_in[8];
    const float* bproj = (const float*)d_in[9];
    const float* g2    = (const float*)d_in[10];
    const float* b2    = (const float*)d_in[11];
    const float* wfc1  = (const float*)d_in[12];
    const float* bfc1  = (const float*)d_in[13];
    const float* wfc2  = (const float*)d_in[14];
    const float* bfc2  = (const float*)d_in[15];

    char* wsb = (char*)d_ws;
    ushort* qkv_bf   = (ushort*)wsb;                           // 19,267,584 B
    ushort* att_bf   = (ushort*)(wsb + 19267584);              //  6,422,528 B
    char*   wbase    = wsb + 19267584 + 6422528;
    ushort* wqkv_bf  = (ushort*)(wbase);
    ushort* wproj_bf = (ushort*)(wbase + 98304);
    ushort* wfc1_bf  = (ushort*)(wbase + 98304 + 32768);
    ushort* wfc2_bf  = (ushort*)(wbase + 98304 + 32768 + 131072);

    float* out = (float*)d_out;

    k_cvt<<<192, 256, 0, stream>>>(wqkv, wproj, wfc1, wfc2, wqkv_bf, wproj_bf, wfc1_bf, wfc2_bf);
    k_ln_qkv<<<GRID, 512, 0, stream>>>(x, g1, b1, wqkv_bf, qkv_bf);
    k_attn_mfma<<<dim3(128, 7), 256, 0, stream>>>(qkv_bf, cw0, cb0, cw1, cb1, att_bf);
    k_pmlp<<<GRID, 512, 0, stream>>>(att_bf, wproj_bf, bproj, x, g2, b2,
                                     wfc1_bf, bfc1, wfc2_bf, bfc2, out);
}